// Round 15
// baseline (3550.740 us; speedup 1.0000x reference)
//
#include <hip/hip_runtime.h>
#include <hip/hip_fp16.h>

#define TT 2048
#define BB 64
#define HH 128
#define GG 512   // 4H
#define CH 64    // chunk (timesteps per handshake)
#define NCH (TT / CH)
#define NPB 32   // producer (= consumer) block count; 2 batches per block

typedef _Float16 f16x8 __attribute__((ext_vector_type(8)));
typedef _Float16 f16x4 __attribute__((ext_vector_type(4)));
typedef float f32x4 __attribute__((ext_vector_type(4)));

__device__ __forceinline__ float sigm(float x) {
    return __builtin_amdgcn_rcpf(1.0f + __expf(-x));
}
__device__ __forceinline__ float tanh_f(float x) {
    return 1.0f - 2.0f * __builtin_amdgcn_rcpf(1.0f + __expf(2.0f * x));
}
// LDS-only barrier: no vmcnt drain.
__device__ __forceinline__ void bar_lds() {
    asm volatile("s_waitcnt lgkmcnt(0)\n\ts_barrier" ::: "memory");
}

__device__ __forceinline__ f16x8 load_frag(const float* rowp, int kt, int lh) {
    const float4* p4 = (const float4*)(rowp + kt * 32 + lh * 8);
    float4 a = p4[0], b = p4[1];
    f16x8 f;
    f[0] = (_Float16)a.x; f[1] = (_Float16)a.y; f[2] = (_Float16)a.z; f[3] = (_Float16)a.w;
    f[4] = (_Float16)b.x; f[5] = (_Float16)b.y; f[6] = (_Float16)b.z; f[7] = (_Float16)b.w;
    return f;
}

// r12's proven producer/consumer protocol + round-15 WAVE-GROUP DUAL-BATCH:
// block = 1024 thr = 16 waves; waves 0-7 run batch p, waves 8-15 run batch
// p+32 with IDENTICAL per-wave workload to r12 (16 MFMA/step, 64 resident
// frag VGPRs, ~100 regs live). 1024-thr blocks force <=128 VGPR (16 waves =
// 4 waves/SIMD minimum) — r14 died because its boundary GEMM spiked to ~165
// and the allocator collapsed to 64 + scratch. Fix: stream Bi one t2-tile at
// a time (unroll 1, 16 live regs; peak ~115 <= 128). Each SIMD now hosts 4
// independent recurrence chains (vs r12's 2) to fill the ~1000 cyc/step of
// dependency stall r12 measured.
__global__ __launch_bounds__(1024, 4) void k_pipe(
    const float* __restrict__ x, const int* __restrict__ lengths,
    const float* __restrict__ ff_w, const float* __restrict__ ff_b,
    const float* __restrict__ W_ih0, const float* __restrict__ W_hh0,
    const float* __restrict__ b0, const float* __restrict__ W_ih1,
    const float* __restrict__ W_hh1, const float* __restrict__ b1,
    _Float16* __restrict__ h0g, int* __restrict__ flags,
    float* __restrict__ pooled) {
    const int tid = threadIdx.x;
    const int w = tid >> 6;
    const int g = w >> 3;           // wave group 0/1 = batch slot
    const int wu = w & 7;           // wave-in-group
    const int lane = tid & 63;
    const int c = lane & 15;
    const int lh = lane >> 4;
    const int un = 16 * wu + c;
    const bool ard = (c == 0);      // A-frag reader lanes (M=1 row 0)
    const bool wr16 = (lane < 16);  // C row m=0 lanes

    __shared__ float xs[2][TT];              // producer: 16 KB
    __shared__ _Float16 Hb0[2][2][HH];       // producer: [grp][buf][unit]
    __shared__ _Float16 Hb1[2][2][HH];       // consumer
    __shared__ _Float16 Qs[2][CH][GG];       // consumer: chunk gates, 128 KB

    if (blockIdx.x < NPB) {
        // ======================= PRODUCER: layer 0 =======================
        const int p = blockIdx.x;
        const int myb = g ? (p + NPB) : p;
        for (int i = tid; i < 2 * TT; i += 1024)
            xs[i >> 11][i & (TT - 1)] = x[((i >> 11) ? (p + NPB) : p) * TT + (i & (TT - 1))];
        if (tid < 4 * HH) ((_Float16*)Hb0)[tid] = (_Float16)0.f;

        f16x8 Bf[4][4];
        float v[4], u0[4];
#pragma unroll
        for (int t2 = 0; t2 < 4; ++t2) {
            const int r = t2 * HH + un;
#pragma unroll
            for (int kt = 0; kt < 4; ++kt) Bf[t2][kt] = load_frag(W_hh0 + r * HH, kt, lh);
            const float4* wi4 = (const float4*)(W_ih0 + r * HH);
            const float4* fw4 = (const float4*)ff_w;
            const float4* fb4 = (const float4*)ff_b;
            float vv = 0.f, uu = 0.f;
#pragma unroll
            for (int m = 0; m < HH / 4; ++m) {
                float4 a = wi4[m], fw = fw4[m], fb = fb4[m];
                vv += a.x * fw.x + a.y * fw.y + a.z * fw.z + a.w * fw.w;
                uu += a.x * fb.x + a.y * fb.y + a.z * fb.z + a.w * fb.w;
            }
            v[t2] = vv;
            u0[t2] = uu + b0[r];
        }
#pragma unroll
        for (int t2 = 0; t2 < 4; ++t2)
#pragma unroll
            for (int kt = 0; kt < 4; ++kt) asm volatile("" : "+v"(Bf[t2][kt]));

        float cst0 = 0.f;
        f16x8 av[4];
#pragma unroll
        for (int kt = 0; kt < 4; ++kt) av[kt] = (f16x8){0, 0, 0, 0, 0, 0, 0, 0};
        __syncthreads();

#define PSTEP(T_, RB_)                                                          \
    do {                                                                        \
        if (ard) {                                                              \
            _Pragma("unroll") for (int kt = 0; kt < 4; ++kt)                    \
                av[kt] = *(const f16x8*)&Hb0[g][RB_][kt * 32 + lh * 8];         \
        }                                                                       \
        const float xt = xs[g][T_];                                             \
        float p4_[4];                                                           \
        _Pragma("unroll") for (int t2 = 0; t2 < 4; ++t2) {                      \
            f32x4 a;                                                            \
            a[0] = wr16 ? (xt * v[t2] + u0[t2]) : 0.f;                          \
            a[1] = 0.f; a[2] = 0.f; a[3] = 0.f;                                 \
            _Pragma("unroll") for (int kt = 0; kt < 4; ++kt)                    \
                a = __builtin_amdgcn_mfma_f32_16x16x32_f16(av[kt], Bf[t2][kt],  \
                                                           a, 0, 0, 0);         \
            p4_[t2] = a[0];                                                     \
        }                                                                       \
        float gi = sigm(p4_[0]), gf = sigm(p4_[1]);                             \
        float gg = tanh_f(p4_[2]), go = sigm(p4_[3]);                           \
        cst0 = gf * cst0 + gi * gg;                                             \
        float hn = go * tanh_f(cst0);                                           \
        if (wr16) {                                                             \
            Hb0[g][(RB_) ^ 1][un] = (_Float16)hn;                               \
            __builtin_nontemporal_store(                                        \
                (_Float16)hn, h0g + ((size_t)myb * TT + (T_)) * HH + un);       \
        }                                                                       \
        bar_lds();                                                              \
    } while (0)

        for (int ch = 0; ch < NCH; ++ch) {
            const int t0 = ch * CH;
            for (int j = 0; j < CH; j += 2) {
                PSTEP(t0 + j, 0);
                PSTEP(t0 + j + 1, 1);
            }
            __syncthreads();  // drain both groups' NT stores before signaling
            if (tid == 0)
                __hip_atomic_store(&flags[p * NCH + ch], ch + 1, __ATOMIC_RELEASE,
                                   __HIP_MEMORY_SCOPE_AGENT);
        }
#undef PSTEP
    } else {
        // ======================= CONSUMER: layer 1 =======================
        const int p = blockIdx.x - NPB;
        const int myb = g ? (p + NPB) : p;
        if (tid < 4 * HH) ((_Float16*)Hb1)[tid] = (_Float16)0.f;

        f16x8 Bh[4][4];
        float bb1[4];
#pragma unroll
        for (int t2 = 0; t2 < 4; ++t2) {
#pragma unroll
            for (int kt = 0; kt < 4; ++kt)
                Bh[t2][kt] = load_frag(W_hh1 + (t2 * HH + un) * HH, kt, lh);
            bb1[t2] = b1[t2 * HH + un];
        }
#pragma unroll
        for (int t2 = 0; t2 < 4; ++t2)
#pragma unroll
            for (int kt = 0; kt < 4; ++kt) asm volatile("" : "+v"(Bh[t2][kt]));

        const int len = lengths[myb];
        float cst1 = 0.f, mean = 0.f, mx = -1e30f, lastv = 0.f;
        f16x8 av[4];
#pragma unroll
        for (int kt = 0; kt < 4; ++kt) av[kt] = (f16x8){0, 0, 0, 0, 0, 0, 0, 0};
        __syncthreads();

#define CSTEP(T_, RB_)                                                          \
    do {                                                                        \
        const int jj = (T_) & (CH - 1);                                         \
        f16x4 qv = *(const f16x4*)&Qs[g][jj][un * 4];                           \
        if (ard) {                                                              \
            _Pragma("unroll") for (int kt = 0; kt < 4; ++kt)                    \
                av[kt] = *(const f16x8*)&Hb1[g][RB_][kt * 32 + lh * 8];         \
        }                                                                       \
        float p4_[4];                                                           \
        _Pragma("unroll") for (int t2 = 0; t2 < 4; ++t2) {                      \
            f32x4 a;                                                            \
            a[0] = wr16 ? (float)qv[t2] : 0.f;                                  \
            a[1] = 0.f; a[2] = 0.f; a[3] = 0.f;                                 \
            _Pragma("unroll") for (int kt = 0; kt < 4; ++kt)                    \
                a = __builtin_amdgcn_mfma_f32_16x16x32_f16(av[kt], Bh[t2][kt],  \
                                                           a, 0, 0, 0);         \
            p4_[t2] = a[0];                                                     \
        }                                                                       \
        float gi = sigm(p4_[0]), gf = sigm(p4_[1]);                             \
        float gg = tanh_f(p4_[2]), go = sigm(p4_[3]);                           \
        cst1 = gf * cst1 + gi * gg;                                             \
        float hn = go * tanh_f(cst1);                                           \
        if (wr16) Hb1[g][(RB_) ^ 1][un] = (_Float16)hn;                         \
        if ((T_) < len) { mean += hn; mx = fmaxf(mx, hn); }                     \
        if ((T_) == len - 1) lastv = hn;                                        \
        bar_lds();                                                              \
    } while (0)

        for (int ch = 0; ch < NCH; ++ch) {
            if (tid == 0) {  // acquire gate
                int guard = 0;
                while (__hip_atomic_load(&flags[p * NCH + ch], __ATOMIC_ACQUIRE,
                                         __HIP_MEMORY_SCOPE_AGENT) != ch + 1) {
                    __builtin_amdgcn_s_sleep(8);
                    if (++guard > (1 << 22)) break;  // hang guard
                }
            }
            __syncthreads();
            // ---- chunk GEMM, Bi STREAMED one t2-tile at a time (16 live
            // regs; a resident Bi[4][4] would spike past the 128-VGPR cap
            // that 1024-thr blocks impose — r14's failure mode) ----
            const _Float16* hbase = h0g + ((size_t)myb * TT + ch * CH) * HH;
#pragma unroll 1
            for (int t2 = 0; t2 < 4; ++t2) {
                f16x8 Bi[4];
#pragma unroll
                for (int kt = 0; kt < 4; ++kt)
                    Bi[kt] = load_frag(W_ih1 + (t2 * HH + un) * HH, kt, lh);
#pragma unroll
                for (int mt = 0; mt < 4; ++mt) {
                    f16x8 am[4];  // A[m=c][k=kt*32+lh*8+j]
#pragma unroll
                    for (int kt = 0; kt < 4; ++kt)
                        am[kt] = *(const f16x8*)(hbase + (mt * 16 + c) * HH + kt * 32 + lh * 8);
                    f32x4 qa = (f32x4){0.f, 0.f, 0.f, 0.f};
#pragma unroll
                    for (int kt = 0; kt < 4; ++kt)
                        qa = __builtin_amdgcn_mfma_f32_16x16x32_f16(am[kt], Bi[kt], qa, 0, 0, 0);
#pragma unroll
                    for (int r = 0; r < 4; ++r)  // C row m = 4*lh + r
                        Qs[g][mt * 16 + 4 * lh + r][un * 4 + t2] =
                            (_Float16)(qa[r] + bb1[t2]);
                }
            }
            __syncthreads();  // Qs visible to all waves
            // ---- 64 recurrence steps, gates from LDS ----
            const int t0 = ch * CH;
            for (int j = 0; j < CH; j += 2) {
                CSTEP(t0 + j, 0);
                CSTEP(t0 + j + 1, 1);
            }
        }
#undef CSTEP
        if (wr16) {
            pooled[myb * 384 + un] = mean / (float)len;
            pooled[myb * 384 + 128 + un] = mx;
            pooled[myb * 384 + 256 + un] = lastv;
        }
    }
}

// ---------------- head: [B,3H] @ [3H,C]^T + bias ----------------
__global__ __launch_bounds__(448) void k_head(
    const float* __restrict__ pooled, const float* __restrict__ lin_w,
    const float* __restrict__ lin_b, float* __restrict__ out) {
    int tid = threadIdx.x;  // 448 = 64*7
    int b = tid / 7, cc = tid % 7;
    const float* p = pooled + b * 384;
    const float* wr = lin_w + cc * 384;
    float a0 = 0.f, a1 = 0.f, a2 = 0.f, a3 = 0.f;
#pragma unroll
    for (int k = 0; k < 384; k += 4) {
        a0 += p[k + 0] * wr[k + 0];
        a1 += p[k + 1] * wr[k + 1];
        a2 += p[k + 2] * wr[k + 2];
        a3 += p[k + 3] * wr[k + 3];
    }
    out[tid] = lin_b[cc] + ((a0 + a1) + (a2 + a3));
}

extern "C" void kernel_launch(void* const* d_in, const int* in_sizes, int n_in,
                              void* d_out, int out_size, void* d_ws, size_t ws_size,
                              hipStream_t stream) {
    const float* x     = (const float*)d_in[0];
    const int*   lens  = (const int*)d_in[1];
    const float* ff_w  = (const float*)d_in[2];
    const float* ff_b  = (const float*)d_in[3];
    const float* W_ih0 = (const float*)d_in[4];
    const float* W_hh0 = (const float*)d_in[5];
    const float* b0    = (const float*)d_in[6];
    const float* W_ih1 = (const float*)d_in[7];
    const float* W_hh1 = (const float*)d_in[8];
    const float* b1    = (const float*)d_in[9];
    const float* lin_w = (const float*)d_in[10];
    const float* lin_b = (const float*)d_in[11];
    float* out = (float*)d_out;

    char* ws = (char*)d_ws;
    const size_t HBYTES = (size_t)BB * TT * HH * 2;  // 32 MB fp16 h0
    _Float16* h0g = (_Float16*)ws;
    int* flags    = (int*)(ws + HBYTES);             // 32*32 ints (poison-safe)
    float* pooled = (float*)(ws + HBYTES + 8192);

    k_pipe<<<dim3(2 * NPB), dim3(1024), 0, stream>>>(
        x, lens, ff_w, ff_b, W_ih0, W_hh0, b0, W_ih1, W_hh1, b1, h0g, flags, pooled);
    k_head<<<dim3(1), dim3(448), 0, stream>>>(pooled, lin_w, lin_b, out);
}

// Round 16
// 1383.404 us; speedup vs baseline: 2.5667x; 2.5667x over previous
//
#include <hip/hip_runtime.h>
#include <hip/hip_fp16.h>

#define TT 2048
#define BB 64
#define HH 128
#define GG 512   // 4H
#define CH 64    // chunk (timesteps per handshake)
#define NCH (TT / CH)

typedef _Float16 f16x8 __attribute__((ext_vector_type(8)));
typedef _Float16 f16x4 __attribute__((ext_vector_type(4)));
typedef float f32x4 __attribute__((ext_vector_type(4)));

__device__ __forceinline__ float sigm(float x) {
    return __builtin_amdgcn_rcpf(1.0f + __expf(-x));
}
__device__ __forceinline__ float tanh_f(float x) {
    return 1.0f - 2.0f * __builtin_amdgcn_rcpf(1.0f + __expf(2.0f * x));
}
// LDS-only barrier: no vmcnt drain (HIP __syncthreads drains all global ops).
__device__ __forceinline__ void bar_lds() {
    asm volatile("s_waitcnt lgkmcnt(0)\n\ts_barrier" ::: "memory");
}

__device__ __forceinline__ f16x8 load_frag(const float* rowp, int kt, int lh) {
    const float4* p4 = (const float4*)(rowp + kt * 32 + lh * 8);
    float4 a = p4[0], b = p4[1];
    f16x8 f;
    f[0] = (_Float16)a.x; f[1] = (_Float16)a.y; f[2] = (_Float16)a.z; f[3] = (_Float16)a.w;
    f[4] = (_Float16)b.x; f[5] = (_Float16)b.y; f[6] = (_Float16)b.z; f[7] = (_Float16)b.w;
    return f;
}

// r12's proven producer/consumer pipeline (champion, 1384 us), FROZEN shape:
// grid 128 x 512 thr, 2 waves/SIMD, 64 resident frag VGPRs/wave. Rounds 13-15
// proved any deviation (fatter waves, 1024-thr blocks) breaks weight
// residency (allocator collapses to 64 VGPR + scratch). Round-16 change is
// INSIDE the step macro only: split the 4-deep MFMA chain into two 2-deep
// chains (alo/ahi, +1 add per t2) to cut ~60-80 cyc of serial MFMA latency
// off the step's critical path, and drop the wr16 ternary on C-init (rows
// 4/8/12 read back init — bounded, discarded).
__global__ __launch_bounds__(512, 1) void k_pipe(
    const float* __restrict__ x, const int* __restrict__ lengths,
    const float* __restrict__ ff_w, const float* __restrict__ ff_b,
    const float* __restrict__ W_ih0, const float* __restrict__ W_hh0,
    const float* __restrict__ b0, const float* __restrict__ W_ih1,
    const float* __restrict__ W_hh1, const float* __restrict__ b1,
    _Float16* __restrict__ h0g, int* __restrict__ flags,
    float* __restrict__ pooled) {
    const int tid = threadIdx.x;
    const int w = tid >> 6;
    const int lane = tid & 63;
    const int c = lane & 15;
    const int lh = lane >> 4;
    const int un = 16 * w + c;
    const bool ard = (c == 0);     // A-frag reader lanes (M=1 row 0)
    const bool wr16 = (lane < 16); // C row m=0 lanes (lh==0)

    __shared__ float xs[TT];                 // producer
    __shared__ _Float16 Hb0[2][HH];          // producer
    __shared__ _Float16 Hb1[2][HH];          // consumer
    __shared__ _Float16 Qs[CH][GG];          // consumer: chunk gates (64 KB)

    if (blockIdx.x < BB) {
        // ======================= PRODUCER: layer 0 =======================
        const int b = blockIdx.x;
        for (int i = tid; i < TT; i += 512) xs[i] = x[b * TT + i];
        if (tid < 2 * HH) ((_Float16*)Hb0)[tid] = (_Float16)0.f;

        f16x8 Bf[4][4];
        float v[4], u0[4];
#pragma unroll
        for (int t2 = 0; t2 < 4; ++t2) {
            const int r = t2 * HH + un;
#pragma unroll
            for (int kt = 0; kt < 4; ++kt) Bf[t2][kt] = load_frag(W_hh0 + r * HH, kt, lh);
            const float4* wi4 = (const float4*)(W_ih0 + r * HH);
            const float4* fw4 = (const float4*)ff_w;
            const float4* fb4 = (const float4*)ff_b;
            float vv = 0.f, uu = 0.f;
#pragma unroll
            for (int m = 0; m < HH / 4; ++m) {
                float4 a = wi4[m], fw = fw4[m], fb = fb4[m];
                vv += a.x * fw.x + a.y * fw.y + a.z * fw.z + a.w * fw.w;
                uu += a.x * fb.x + a.y * fb.y + a.z * fb.z + a.w * fb.w;
            }
            v[t2] = vv;
            u0[t2] = uu + b0[r];
        }
#pragma unroll
        for (int t2 = 0; t2 < 4; ++t2)
#pragma unroll
            for (int kt = 0; kt < 4; ++kt) asm volatile("" : "+v"(Bf[t2][kt]));

        float cst0 = 0.f;
        f16x8 av[4];
#pragma unroll
        for (int kt = 0; kt < 4; ++kt) av[kt] = (f16x8){0, 0, 0, 0, 0, 0, 0, 0};
        __syncthreads();

#define PSTEP(T_, RB_)                                                          \
    do {                                                                        \
        if (ard) {                                                              \
            _Pragma("unroll") for (int kt = 0; kt < 4; ++kt)                    \
                av[kt] = *(const f16x8*)&Hb0[RB_][kt * 32 + lh * 8];            \
        }                                                                       \
        const float xt = xs[T_];                                                \
        float p[4];                                                             \
        _Pragma("unroll") for (int t2 = 0; t2 < 4; ++t2) {                      \
            f32x4 alo, ahi;                                                     \
            const float ci = xt * v[t2] + u0[t2];                               \
            alo[0] = ci;  alo[1] = 0.f; alo[2] = 0.f; alo[3] = 0.f;             \
            ahi[0] = 0.f; ahi[1] = 0.f; ahi[2] = 0.f; ahi[3] = 0.f;             \
            alo = __builtin_amdgcn_mfma_f32_16x16x32_f16(av[0], Bf[t2][0],      \
                                                         alo, 0, 0, 0);         \
            ahi = __builtin_amdgcn_mfma_f32_16x16x32_f16(av[2], Bf[t2][2],      \
                                                         ahi, 0, 0, 0);         \
            alo = __builtin_amdgcn_mfma_f32_16x16x32_f16(av[1], Bf[t2][1],      \
                                                         alo, 0, 0, 0);         \
            ahi = __builtin_amdgcn_mfma_f32_16x16x32_f16(av[3], Bf[t2][3],      \
                                                         ahi, 0, 0, 0);         \
            p[t2] = alo[0] + ahi[0];                                            \
        }                                                                       \
        float gi = sigm(p[0]), gf = sigm(p[1]);                                 \
        float gg = tanh_f(p[2]), go = sigm(p[3]);                               \
        cst0 = gf * cst0 + gi * gg;                                             \
        float h0n = go * tanh_f(cst0);                                          \
        if (wr16) {                                                             \
            Hb0[(RB_) ^ 1][un] = (_Float16)h0n;                                 \
            __builtin_nontemporal_store(                                        \
                (_Float16)h0n, h0g + ((size_t)b * TT + (T_)) * HH + un);        \
        }                                                                       \
        bar_lds();                                                              \
    } while (0)

        for (int ch = 0; ch < NCH; ++ch) {
            const int t0 = ch * CH;
            for (int j = 0; j < CH; j += 2) {
                PSTEP(t0 + j, 0);
                PSTEP(t0 + j + 1, 1);
            }
            __syncthreads();  // drain every wave's h0 NT stores before signaling
            if (tid == 0)
                __hip_atomic_store(&flags[b * NCH + ch], ch + 1, __ATOMIC_RELEASE,
                                   __HIP_MEMORY_SCOPE_AGENT);
        }
#undef PSTEP
    } else {
        // ======================= CONSUMER: layer 1 =======================
        const int b = blockIdx.x - BB;
        if (tid < 2 * HH) ((_Float16*)Hb1)[tid] = (_Float16)0.f;

        f16x8 Bh[4][4];
        float bb1[4];
#pragma unroll
        for (int t2 = 0; t2 < 4; ++t2) {
#pragma unroll
            for (int kt = 0; kt < 4; ++kt)
                Bh[t2][kt] = load_frag(W_hh1 + (t2 * HH + un) * HH, kt, lh);
            bb1[t2] = b1[t2 * HH + un];
        }
#pragma unroll
        for (int t2 = 0; t2 < 4; ++t2)
#pragma unroll
            for (int kt = 0; kt < 4; ++kt) asm volatile("" : "+v"(Bh[t2][kt]));

        const int len = lengths[b];
        float cst1 = 0.f, mean = 0.f, mx = -1e30f, last = 0.f;
        f16x8 av[4];
#pragma unroll
        for (int kt = 0; kt < 4; ++kt) av[kt] = (f16x8){0, 0, 0, 0, 0, 0, 0, 0};
        __syncthreads();

#define CSTEP(T_, RB_)                                                          \
    do {                                                                        \
        const int jj = (T_) & (CH - 1);                                         \
        f16x4 qv = *(const f16x4*)&Qs[jj][un * 4]; /* all lanes: broadcast */   \
        if (ard) {                                                              \
            _Pragma("unroll") for (int kt = 0; kt < 4; ++kt)                    \
                av[kt] = *(const f16x8*)&Hb1[RB_][kt * 32 + lh * 8];            \
        }                                                                       \
        float p[4];                                                             \
        _Pragma("unroll") for (int t2 = 0; t2 < 4; ++t2) {                      \
            f32x4 alo, ahi;                                                     \
            alo[0] = (float)qv[t2];                                             \
            alo[1] = 0.f; alo[2] = 0.f; alo[3] = 0.f;                           \
            ahi[0] = 0.f; ahi[1] = 0.f; ahi[2] = 0.f; ahi[3] = 0.f;             \
            alo = __builtin_amdgcn_mfma_f32_16x16x32_f16(av[0], Bh[t2][0],      \
                                                         alo, 0, 0, 0);         \
            ahi = __builtin_amdgcn_mfma_f32_16x16x32_f16(av[2], Bh[t2][2],      \
                                                         ahi, 0, 0, 0);         \
            alo = __builtin_amdgcn_mfma_f32_16x16x32_f16(av[1], Bh[t2][1],      \
                                                         alo, 0, 0, 0);         \
            ahi = __builtin_amdgcn_mfma_f32_16x16x32_f16(av[3], Bh[t2][3],      \
                                                         ahi, 0, 0, 0);         \
            p[t2] = alo[0] + ahi[0];                                            \
        }                                                                       \
        float gi = sigm(p[0]), gf = sigm(p[1]);                                 \
        float gg = tanh_f(p[2]), go = sigm(p[3]);                               \
        cst1 = gf * cst1 + gi * gg;                                             \
        float h1n = go * tanh_f(cst1);                                          \
        if (wr16) Hb1[(RB_) ^ 1][un] = (_Float16)h1n;                           \
        if ((T_) < len) {                                                       \
            mean += h1n;                                                        \
            mx = fmaxf(mx, h1n);                                                \
        }                                                                       \
        if ((T_) == len - 1) last = h1n;                                        \
        bar_lds();                                                              \
    } while (0)

        for (int ch = 0; ch < NCH; ++ch) {
            if (tid == 0) {  // acquire gate
                int guard = 0;
                while (__hip_atomic_load(&flags[b * NCH + ch], __ATOMIC_ACQUIRE,
                                         __HIP_MEMORY_SCOPE_AGENT) != ch + 1) {
                    __builtin_amdgcn_s_sleep(8);
                    if (++guard > (1 << 22)) break;  // hang guard
                }
            }
            __syncthreads();
            // ---- chunk GEMM: Qs[j][un*4+t2] = b1 + W_ih1 . h0[t0+j] ----
            f16x8 Bi[4][4];  // reloaded per chunk (keeps step-loop pressure low)
#pragma unroll
            for (int t2 = 0; t2 < 4; ++t2)
#pragma unroll
                for (int kt = 0; kt < 4; ++kt)
                    Bi[t2][kt] = load_frag(W_ih1 + (t2 * HH + un) * HH, kt, lh);
            const _Float16* hbase = h0g + ((size_t)b * TT + ch * CH) * HH;
#pragma unroll
            for (int mt = 0; mt < 4; ++mt) {
                f16x8 am[4];  // A[m=c][k=kt*32+lh*8+j]
#pragma unroll
                for (int kt = 0; kt < 4; ++kt)
                    am[kt] = *(const f16x8*)(hbase + (mt * 16 + c) * HH + kt * 32 + lh * 8);
                f32x4 qa[4];
#pragma unroll
                for (int t2 = 0; t2 < 4; ++t2) {
                    qa[t2] = (f32x4){0.f, 0.f, 0.f, 0.f};
#pragma unroll
                    for (int kt = 0; kt < 4; ++kt)
                        qa[t2] = __builtin_amdgcn_mfma_f32_16x16x32_f16(
                            am[kt], Bi[t2][kt], qa[t2], 0, 0, 0);
                }
#pragma unroll
                for (int r = 0; r < 4; ++r) {  // C row m = 4*lh + r
                    f16x4 qv;
#pragma unroll
                    for (int t2 = 0; t2 < 4; ++t2) qv[t2] = (_Float16)(qa[t2][r] + bb1[t2]);
                    *(f16x4*)&Qs[mt * 16 + 4 * lh + r][un * 4] = qv;
                }
            }
            __syncthreads();  // Qs visible to all waves
            // ---- 64 recurrence steps, gates from LDS ----
            const int t0 = ch * CH;
            for (int j = 0; j < CH; j += 2) {
                CSTEP(t0 + j, 0);
                CSTEP(t0 + j + 1, 1);
            }
        }
#undef CSTEP
        if (wr16) {
            pooled[b * 384 + un] = mean / (float)len;
            pooled[b * 384 + 128 + un] = mx;
            pooled[b * 384 + 256 + un] = last;
        }
    }
}

// ---------------- head: [B,3H] @ [3H,C]^T + bias ----------------
__global__ __launch_bounds__(448) void k_head(
    const float* __restrict__ pooled, const float* __restrict__ lin_w,
    const float* __restrict__ lin_b, float* __restrict__ out) {
    int tid = threadIdx.x;  // 448 = 64*7
    int b = tid / 7, cc = tid % 7;
    const float* p = pooled + b * 384;
    const float* wr = lin_w + cc * 384;
    float a0 = 0.f, a1 = 0.f, a2 = 0.f, a3 = 0.f;
#pragma unroll
    for (int k = 0; k < 384; k += 4) {
        a0 += p[k + 0] * wr[k + 0];
        a1 += p[k + 1] * wr[k + 1];
        a2 += p[k + 2] * wr[k + 2];
        a3 += p[k + 3] * wr[k + 3];
    }
    out[tid] = lin_b[cc] + ((a0 + a1) + (a2 + a3));
}

extern "C" void kernel_launch(void* const* d_in, const int* in_sizes, int n_in,
                              void* d_out, int out_size, void* d_ws, size_t ws_size,
                              hipStream_t stream) {
    const float* x     = (const float*)d_in[0];
    const int*   lens  = (const int*)d_in[1];
    const float* ff_w  = (const float*)d_in[2];
    const float* ff_b  = (const float*)d_in[3];
    const float* W_ih0 = (const float*)d_in[4];
    const float* W_hh0 = (const float*)d_in[5];
    const float* b0    = (const float*)d_in[6];
    const float* W_ih1 = (const float*)d_in[7];
    const float* W_hh1 = (const float*)d_in[8];
    const float* b1    = (const float*)d_in[9];
    const float* lin_w = (const float*)d_in[10];
    const float* lin_b = (const float*)d_in[11];
    float* out = (float*)d_out;

    char* ws = (char*)d_ws;
    const size_t HBYTES = (size_t)BB * TT * HH * 2;  // 32 MB fp16 h0
    _Float16* h0g = (_Float16*)ws;
    int* flags    = (int*)(ws + HBYTES);             // 64*32 ints (poison-safe)
    float* pooled = (float*)(ws + HBYTES + 8192);

    k_pipe<<<dim3(2 * BB), dim3(512), 0, stream>>>(
        x, lens, ff_w, ff_b, W_ih0, W_hh0, b0, W_ih1, W_hh1, b1, h0g, flags, pooled);
    k_head<<<dim3(1), dim3(448), 0, stream>>>(pooled, lin_w, lin_b, out);
}